// Round 3
// baseline (93.152 us; speedup 1.0000x reference)
//
#include <hip/hip_runtime.h>
#include <math.h>

// Exact fusion of: resize(256->1024) -> warp_perspective(affine) -> resize(1024->256).
// out[b,c,i,j] = 0.25 * sum_{dy,dx in {1,2}} WarpSample(Y=4i+dy, X=4j+dx)
// Each warp sample is a separable 3x3 stencil on the 256-res source; the two
// dx-samples of a row pair merge into one 4x4 window (rank-2 weights), loaded
// as 4 float4 rows. This round: both p-windows' weights/addresses are computed
// up front and all 24 gathers issued as one group (latency overlap), minv read
// as float4+float2.

typedef float floatx4 __attribute__((ext_vector_type(4)));
typedef float floatx2 __attribute__((ext_vector_type(2)));

__device__ __forceinline__ floatx4 load4(const float* p) {
    floatx4 v;
    __builtin_memcpy(&v, p, sizeof(v));  // 4B-aligned 16B load -> dwordx4
    return v;
}

__global__ __launch_bounds__(64) void compute_minv(
    const float* __restrict__ paramP, const float* __restrict__ paramM,
    const float* __restrict__ gumbel_u, const float* __restrict__ eps,
    const int* __restrict__ idx, float* __restrict__ minv, int N)
{
    int b = threadIdx.x;
    if (b >= 16) return;
    int id = idx[b];
    float sP[7], sM[7];
#pragma unroll
    for (int k = 0; k < 7; ++k) {
        float vP = paramP[k * N + id];
        float pP = 1.0f / (1.0f + expf(-vP));
        float l0 = logf(pP);
        float l1 = logf(1.0f - pP);
        float u0 = gumbel_u[(k * 16 + b) * 2 + 0];
        float u1 = gumbel_u[(k * 16 + b) * 2 + 1];
        float g0 = -logf(-logf(u0));
        float g1 = -logf(-logf(u1));
        sP[k] = (l0 + g0 >= l1 + g1) ? 1.0f : 0.0f;  // argmax tie -> index 0
        float vM = paramM[k * N + id];
        float sig = 1.0f / (1.0f + expf(-vM));
        sM[k] = sig * eps[k * 16 + b];
    }
    float ang = sP[0] * sM[0] * 30.0f;
    float rad = ang * 0.017453292519943295f;
    float ca = cosf(rad), sa = sinf(rad);
    float sx = 1.0f + sP[5] * sM[5] * 0.5f;
    float sy = 1.0f + sP[6] * sM[6] * 0.5f;
    float sr00 = ca * sx, sr01 = sa * sy;
    float sr10 = -sa * sx, sr11 = ca * sy;
    float t0 = 128.0f - (sr00 + sr01) * 128.0f;
    float t1 = 128.0f - (sr10 + sr11) * 128.0f;
    float tx = 256.0f * sP[1] * sM[1] * 0.45f;
    float ty = 256.0f * sP[2] * sM[2] * 0.45f;
    float sh01 = sP[3] * sM[3] * 0.3f;
    float sh10 = sP[4] * sM[4] * 0.3f;
    float e0 = t0 + tx, e1 = t1 + ty;
    float a  = sr00 + sh01 * sr10;
    float bb = sr01 + sh01 * sr11;
    float txm = e0 + sh01 * e1;
    float c  = sh10 * sr00 + sr10;
    float d  = sh10 * sr01 + sr11;
    float tym = sh10 * e0 + e1;
    float det = a * d - bb * c;
    float rdet = 1.0f / det;
    float* o = minv + b * 8;
    o[0] = d * rdet;
    o[1] = -bb * rdet;
    o[2] = (bb * tym - d * txm) * rdet;
    o[3] = -c * rdet;
    o[4] = a * rdet;
    o[5] = (c * txm - a * tym) * rdet;
    o[6] = 0.f;
    o[7] = 0.f;
}

struct Up { int i0; float w; };

// up-resize coord for 1024-res integer index v: u = 0.25*v - 0.375, clipped
// to [0,255]. At the clip boundaries the fractional weight is exactly 0.
__device__ __forceinline__ Up upc(int v) {
    float u = fmaf(0.25f, (float)v, -0.375f);
    u = fminf(fmaxf(u, 0.0f), 255.0f);
    float f = floorf(u);
    Up r; r.i0 = (int)f; r.w = u - f;
    return r;
}

struct Trip { float w0, w1, w2; int base; };

// merged 3-tap weights (outer bilinear x inner up-bilinear) along one axis,
// for a clipped fine coordinate s in [0,1023].
__device__ __forceinline__ Trip merged3(float s) {
    float f = floorf(s);
    float fr = s - f;
    int v0 = (int)f;
    int v1 = min(v0 + 1, 1023);
    Up c0 = upc(v0), c1 = upc(v1);
    float A0 = 1.0f - fr, A1 = fr;
    float b0 = A1 * (1.0f - c1.w), b1 = A1 * c1.w;
    bool d = (c1.i0 != c0.i0);
    Trip t;
    t.w0 = A0 * (1.0f - c0.w) + (d ? 0.0f : b0);
    t.w1 = A0 * c0.w + (d ? b0 : b1);
    t.w2 = d ? b1 : 0.0f;
    t.base = c0.i0;
    return t;
}

struct PairWin {
    float W[4][4];
    int e[4];  // per-row element offsets (row*256 + col base)
};

// Build the merged 4x4 window for the sample pair (xAu,yAu) and
// (xAu+m00, yAu+m10), both clipped to [0,1023].
__device__ __forceinline__ PairWin make_window(float xAu, float yAu,
                                               float m00, float m10) {
    float xBu = xAu + m00;
    float yBu = yAu + m10;
    float xsA = fminf(fmaxf(xAu, 0.f), 1023.f);
    float ysA = fminf(fmaxf(yAu, 0.f), 1023.f);
    float xsB = fminf(fmaxf(xBu, 0.f), 1023.f);
    float ysB = fminf(fmaxf(yBu, 0.f), 1023.f);
    Trip cA = merged3(xsA), cB = merged3(xsB);
    Trip rA = merged3(ysA), rB = merged3(ysB);
    int cb = min(cA.base, cB.base);
    int rb = min(rA.base, rB.base);
    float CA[4], CB[4], RA[4], RB[4];
    bool sa_ = (cA.base != cb);
    CA[0] = sa_ ? 0.f : cA.w0;
    CA[1] = sa_ ? cA.w0 : cA.w1;
    CA[2] = sa_ ? cA.w1 : cA.w2;
    CA[3] = sa_ ? cA.w2 : 0.f;
    bool sb_ = (cB.base != cb);
    CB[0] = sb_ ? 0.f : cB.w0;
    CB[1] = sb_ ? cB.w0 : cB.w1;
    CB[2] = sb_ ? cB.w1 : cB.w2;
    CB[3] = sb_ ? cB.w2 : 0.f;
    bool ra_ = (rA.base != rb);
    RA[0] = ra_ ? 0.f : rA.w0;
    RA[1] = ra_ ? rA.w0 : rA.w1;
    RA[2] = ra_ ? rA.w1 : rA.w2;
    RA[3] = ra_ ? rA.w2 : 0.f;
    bool rb_ = (rB.base != rb);
    RB[0] = rb_ ? 0.f : rB.w0;
    RB[1] = rb_ ? rB.w0 : rB.w1;
    RB[2] = rb_ ? rB.w1 : rB.w2;
    RB[3] = rb_ ? rB.w2 : 0.f;

    PairWin pw;
#pragma unroll
    for (int r = 0; r < 4; ++r)
#pragma unroll
        for (int c = 0; c < 4; ++c)
            pw.W[r][c] = fmaf(RB[r], CB[c], RA[r] * CA[c]);

    // right-edge safety: keep the float4 load inside the channel row.
    // Weights for columns > 255 are exactly zero, so rotating them right
    // against a base of 252 is exact. shift <= 3.
    int base = cb;
    if (cb > 252) {
        int shift = cb - 252;
        base = 252;
        for (int s = 0; s < shift; ++s) {
#pragma unroll
            for (int r = 0; r < 4; ++r) {
                pw.W[r][3] = pw.W[r][2];
                pw.W[r][2] = pw.W[r][1];
                pw.W[r][1] = pw.W[r][0];
                pw.W[r][0] = 0.f;
            }
        }
    }

    pw.e[0] = rb * 256 + base;
    pw.e[1] = min(rb + 1, 255) * 256 + base;  // rows past 255 carry zero
    pw.e[2] = min(rb + 2, 255) * 256 + base;  //   weight; aliasing row 255
    pw.e[3] = min(rb + 3, 255) * 256 + base;  //   is harmless
    return pw;
}

__global__ __launch_bounds__(256) void fused_warp(
    const float* __restrict__ x, const float* __restrict__ minv,
    float* __restrict__ out)
{
    int j = blockIdx.x * 16 + threadIdx.x;
    int i = blockIdx.y * 16 + threadIdx.y;
    int b = blockIdx.z;

    // minv: 2 vector loads instead of 6 scalar loads at the chain head
    floatx4 mA;
    __builtin_memcpy(&mA, minv + b * 8, sizeof(mA));
    floatx2 mB;
    __builtin_memcpy(&mB, minv + b * 8 + 4, sizeof(mB));
    float m00 = mA.x, m01 = mA.y, m02 = mA.z;
    float m10 = mA.w, m11 = mB.x, m12 = mB.y;

    const float* xb = x + b * 3 * 65536;

    float XA = (float)(4 * j + 1);
    float Y0 = (float)(4 * i + 1);
    float Y1 = (float)(4 * i + 2);

    // both windows' weights + addresses up front
    PairWin w0 = make_window(fmaf(m00, XA, fmaf(m01, Y0, m02)),
                             fmaf(m10, XA, fmaf(m11, Y0, m12)), m00, m10);
    PairWin w1 = make_window(fmaf(m00, XA, fmaf(m01, Y1, m02)),
                             fmaf(m10, XA, fmaf(m11, Y1, m12)), m00, m10);

    // issue all 24 gathers as one group
    floatx4 L0[4][3], L1[4][3];
#pragma unroll
    for (int r = 0; r < 4; ++r)
#pragma unroll
        for (int ch = 0; ch < 3; ++ch)
            L0[r][ch] = load4(xb + ch * 65536 + w0.e[r]);
#pragma unroll
    for (int r = 0; r < 4; ++r)
#pragma unroll
        for (int ch = 0; ch < 3; ++ch)
            L1[r][ch] = load4(xb + ch * 65536 + w1.e[r]);

    float acc[3];
#pragma unroll
    for (int ch = 0; ch < 3; ++ch) {
        float s = 0.f;
#pragma unroll
        for (int r = 0; r < 4; ++r) {
            floatx4 v = L0[r][ch];
            s = fmaf(w0.W[r][0], v.x, s);
            s = fmaf(w0.W[r][1], v.y, s);
            s = fmaf(w0.W[r][2], v.z, s);
            s = fmaf(w0.W[r][3], v.w, s);
        }
#pragma unroll
        for (int r = 0; r < 4; ++r) {
            floatx4 v = L1[r][ch];
            s = fmaf(w1.W[r][0], v.x, s);
            s = fmaf(w1.W[r][1], v.y, s);
            s = fmaf(w1.W[r][2], v.z, s);
            s = fmaf(w1.W[r][3], v.w, s);
        }
        acc[ch] = s;
    }

    int obase = ((b * 3) * 256 + i) * 256 + j;
    out[obase]          = 0.25f * acc[0];
    out[obase + 65536]  = 0.25f * acc[1];
    out[obase + 131072] = 0.25f * acc[2];
}

extern "C" void kernel_launch(void* const* d_in, const int* in_sizes, int n_in,
                              void* d_out, int out_size, void* d_ws, size_t ws_size,
                              hipStream_t stream) {
    const float* x      = (const float*)d_in[0];
    const float* paramP = (const float*)d_in[1];
    const float* paramM = (const float*)d_in[2];
    const float* gumbel = (const float*)d_in[3];
    const float* eps    = (const float*)d_in[4];
    const int*   idx    = (const int*)d_in[5];
    float* out  = (float*)d_out;
    float* minv = (float*)d_ws;
    int N = in_sizes[1] / 7;

    hipLaunchKernelGGL(compute_minv, dim3(1), dim3(64), 0, stream,
                       paramP, paramM, gumbel, eps, idx, minv, N);
    hipLaunchKernelGGL(fused_warp, dim3(16, 16, 16), dim3(16, 16, 1), 0, stream,
                       x, minv, out);
}

// Round 4
// 88.751 us; speedup vs baseline: 1.0496x; 1.0496x over previous
//
#include <hip/hip_runtime.h>
#include <math.h>

// Exact fusion of: resize(256->1024) -> warp_perspective(affine) -> resize(1024->256),
// with the per-batch inverse-matrix computation fused into every block (lanes 0-6
// of wave 0 compute the gumbel decisions in parallel; lane 0 assembles the affine
// inverse; broadcast via LDS). Body identical to the round-2 structure (best so
// far): per row-pair p, one merged 4x4 window, 12 float4 gathers issued and
// consumed per p (interleaved -> low register pressure, ~5 waves/SIMD).

typedef float floatx4 __attribute__((ext_vector_type(4)));

__device__ __forceinline__ floatx4 load4(const float* p) {
    floatx4 v;
    __builtin_memcpy(&v, p, sizeof(v));  // 4B-aligned 16B load -> dwordx4
    return v;
}

struct Up { int i0; float w; };

// up-resize coord for 1024-res integer index v: u = 0.25*v - 0.375, clipped
// to [0,255]. At the clip boundaries the fractional weight is exactly 0.
__device__ __forceinline__ Up upc(int v) {
    float u = fmaf(0.25f, (float)v, -0.375f);
    u = fminf(fmaxf(u, 0.0f), 255.0f);
    float f = floorf(u);
    Up r; r.i0 = (int)f; r.w = u - f;
    return r;
}

struct Trip { float w0, w1, w2; int base; };

// merged 3-tap weights (outer bilinear x inner up-bilinear) along one axis,
// for a clipped fine coordinate s in [0,1023].
__device__ __forceinline__ Trip merged3(float s) {
    float f = floorf(s);
    float fr = s - f;
    int v0 = (int)f;
    int v1 = min(v0 + 1, 1023);
    Up c0 = upc(v0), c1 = upc(v1);
    float A0 = 1.0f - fr, A1 = fr;
    float b0 = A1 * (1.0f - c1.w), b1 = A1 * c1.w;
    bool d = (c1.i0 != c0.i0);
    Trip t;
    t.w0 = A0 * (1.0f - c0.w) + (d ? 0.0f : b0);
    t.w1 = A0 * c0.w + (d ? b0 : b1);
    t.w2 = d ? b1 : 0.0f;
    t.base = c0.i0;
    return t;
}

__global__ __launch_bounds__(256) void fused_warp(
    const float* __restrict__ x,
    const float* __restrict__ paramP, const float* __restrict__ paramM,
    const float* __restrict__ gumbel_u, const float* __restrict__ eps,
    const int* __restrict__ idx,
    float* __restrict__ out, int N)
{
    __shared__ float smem[8];

    int b = blockIdx.z;
    int tid = threadIdx.y * 16 + threadIdx.x;

    // ---- per-block inverse-matrix computation (wave 0 only) ----
    if (tid < 64) {
        float dec = 0.f, sMv = 0.f;
        if (tid < 7) {
            int k = tid;
            int id = idx[b];
            float vP = paramP[k * N + id];
            float pP = 1.0f / (1.0f + expf(-vP));
            float l0 = logf(pP);
            float l1 = logf(1.0f - pP);
            float u0 = gumbel_u[(k * 16 + b) * 2 + 0];
            float u1 = gumbel_u[(k * 16 + b) * 2 + 1];
            float g0 = -logf(-logf(u0));
            float g1 = -logf(-logf(u1));
            dec = (l0 + g0 >= l1 + g1) ? 1.0f : 0.0f;  // argmax tie -> index 0
            float vM = paramM[k * N + id];
            float sig = 1.0f / (1.0f + expf(-vM));
            sMv = sig * eps[k * 16 + b];
        }
        // gather the 7 (decision, magnitude) pairs into every lane
        float sP[7], sM[7];
#pragma unroll
        for (int k = 0; k < 7; ++k) {
            sP[k] = __shfl(dec, k, 64);
            sM[k] = __shfl(sMv, k, 64);
        }
        if (tid == 0) {
            float ang = sP[0] * sM[0] * 30.0f;
            float rad = ang * 0.017453292519943295f;
            float ca = cosf(rad), sa = sinf(rad);
            float sx = 1.0f + sP[5] * sM[5] * 0.5f;
            float sy = 1.0f + sP[6] * sM[6] * 0.5f;
            float sr00 = ca * sx, sr01 = sa * sy;
            float sr10 = -sa * sx, sr11 = ca * sy;
            float t0 = 128.0f - (sr00 + sr01) * 128.0f;
            float t1 = 128.0f - (sr10 + sr11) * 128.0f;
            float tx = 256.0f * sP[1] * sM[1] * 0.45f;
            float ty = 256.0f * sP[2] * sM[2] * 0.45f;
            float sh01 = sP[3] * sM[3] * 0.3f;
            float sh10 = sP[4] * sM[4] * 0.3f;
            float e0 = t0 + tx, e1 = t1 + ty;
            float a  = sr00 + sh01 * sr10;
            float bb = sr01 + sh01 * sr11;
            float txm = e0 + sh01 * e1;
            float c  = sh10 * sr00 + sr10;
            float d  = sh10 * sr01 + sr11;
            float tym = sh10 * e0 + e1;
            float det = a * d - bb * c;
            float rdet = 1.0f / det;
            smem[0] = d * rdet;
            smem[1] = -bb * rdet;
            smem[2] = (bb * tym - d * txm) * rdet;
            smem[3] = -c * rdet;
            smem[4] = a * rdet;
            smem[5] = (c * txm - a * tym) * rdet;
        }
    }
    __syncthreads();

    float m00 = smem[0], m01 = smem[1], m02 = smem[2];
    float m10 = smem[3], m11 = smem[4], m12 = smem[5];

    int j = blockIdx.x * 16 + threadIdx.x;
    int i = blockIdx.y * 16 + threadIdx.y;
    const float* xb = x + b * 3 * 65536;
    float acc[3] = {0.f, 0.f, 0.f};

#pragma unroll
    for (int p = 0; p < 2; ++p) {
        // sample A: X = 4j+1, sample B: X = 4j+2, shared Y = 4i+1+p
        float XA = (float)(4 * j + 1);
        float Yp = (float)(4 * i + 1 + p);
        float xAu = fmaf(m00, XA, fmaf(m01, Yp, m02));
        float yAu = fmaf(m10, XA, fmaf(m11, Yp, m12));
        float xBu = xAu + m00;
        float yBu = yAu + m10;
        float xsA = fminf(fmaxf(xAu, 0.f), 1023.f);
        float ysA = fminf(fmaxf(yAu, 0.f), 1023.f);
        float xsB = fminf(fmaxf(xBu, 0.f), 1023.f);
        float ysB = fminf(fmaxf(yBu, 0.f), 1023.f);
        Trip cA = merged3(xsA), cB = merged3(xsB);
        Trip rA = merged3(ysA), rB = merged3(ysB);
        int cb = min(cA.base, cB.base);
        int rb = min(rA.base, rB.base);
        // place each 3-tap vector in the 4-wide union window (offset 0 or 1)
        float CA[4], CB[4], RA[4], RB[4];
        bool sa_ = (cA.base != cb);
        CA[0] = sa_ ? 0.f : cA.w0;
        CA[1] = sa_ ? cA.w0 : cA.w1;
        CA[2] = sa_ ? cA.w1 : cA.w2;
        CA[3] = sa_ ? cA.w2 : 0.f;
        bool sb_ = (cB.base != cb);
        CB[0] = sb_ ? 0.f : cB.w0;
        CB[1] = sb_ ? cB.w0 : cB.w1;
        CB[2] = sb_ ? cB.w1 : cB.w2;
        CB[3] = sb_ ? cB.w2 : 0.f;
        bool ra_ = (rA.base != rb);
        RA[0] = ra_ ? 0.f : rA.w0;
        RA[1] = ra_ ? rA.w0 : rA.w1;
        RA[2] = ra_ ? rA.w1 : rA.w2;
        RA[3] = ra_ ? rA.w2 : 0.f;
        bool rb_ = (rB.base != rb);
        RB[0] = rb_ ? 0.f : rB.w0;
        RB[1] = rb_ ? rB.w0 : rB.w1;
        RB[2] = rb_ ? rB.w1 : rB.w2;
        RB[3] = rb_ ? rB.w2 : 0.f;

        float W[4][4];
#pragma unroll
        for (int r = 0; r < 4; ++r)
#pragma unroll
            for (int c = 0; c < 4; ++c)
                W[r][c] = fmaf(RB[r], CB[c], RA[r] * CA[c]);

        // right-edge safety: keep the float4 load inside the channel row.
        // Weights for columns > 255 are exactly zero, so rotating them right
        // against a base of 252 is exact. shift <= 3.
        int base = cb;
        if (cb > 252) {
            int shift = cb - 252;
            base = 252;
            for (int s = 0; s < shift; ++s) {
#pragma unroll
                for (int r = 0; r < 4; ++r) {
                    W[r][3] = W[r][2];
                    W[r][2] = W[r][1];
                    W[r][1] = W[r][0];
                    W[r][0] = 0.f;
                }
            }
        }

        int e0 = rb * 256 + base;                 // rb in [0,255]
        int e1 = min(rb + 1, 255) * 256 + base;   // rows past 255 carry zero
        int e2 = min(rb + 2, 255) * 256 + base;   //   weight; aliasing row 255
        int e3 = min(rb + 3, 255) * 256 + base;   //   is harmless

#pragma unroll
        for (int ch = 0; ch < 3; ++ch) {
            const float* pc = xb + ch * 65536;
            floatx4 L0 = load4(pc + e0);
            floatx4 L1 = load4(pc + e1);
            floatx4 L2 = load4(pc + e2);
            floatx4 L3 = load4(pc + e3);
            float s0 = fmaf(W[0][3], L0.w, fmaf(W[0][2], L0.z, fmaf(W[0][1], L0.y, W[0][0] * L0.x)));
            float s1 = fmaf(W[1][3], L1.w, fmaf(W[1][2], L1.z, fmaf(W[1][1], L1.y, W[1][0] * L1.x)));
            float s2 = fmaf(W[2][3], L2.w, fmaf(W[2][2], L2.z, fmaf(W[2][1], L2.y, W[2][0] * L2.x)));
            float s3 = fmaf(W[3][3], L3.w, fmaf(W[3][2], L3.z, fmaf(W[3][1], L3.y, W[3][0] * L3.x)));
            acc[ch] += (s0 + s1) + (s2 + s3);
        }
    }

    int obase = ((b * 3) * 256 + i) * 256 + j;
    out[obase]          = 0.25f * acc[0];
    out[obase + 65536]  = 0.25f * acc[1];
    out[obase + 131072] = 0.25f * acc[2];
}

extern "C" void kernel_launch(void* const* d_in, const int* in_sizes, int n_in,
                              void* d_out, int out_size, void* d_ws, size_t ws_size,
                              hipStream_t stream) {
    const float* x      = (const float*)d_in[0];
    const float* paramP = (const float*)d_in[1];
    const float* paramM = (const float*)d_in[2];
    const float* gumbel = (const float*)d_in[3];
    const float* eps    = (const float*)d_in[4];
    const int*   idx    = (const int*)d_in[5];
    float* out  = (float*)d_out;
    int N = in_sizes[1] / 7;

    hipLaunchKernelGGL(fused_warp, dim3(16, 16, 16), dim3(16, 16, 1), 0, stream,
                       x, paramP, paramM, gumbel, eps, idx, out, N);
}